// Round 15
// baseline (532.517 us; speedup 1.0000x reference)
//
#include <hip/hip_runtime.h>
#include <hip/hip_bf16.h>

typedef __attribute__((ext_vector_type(8))) __bf16 bf16x8;
typedef __attribute__((ext_vector_type(4))) float f32x4;
typedef __attribute__((ext_vector_type(4))) int i32x4;
typedef __attribute__((ext_vector_type(4))) unsigned short u16x4;

#define MFMA16(a, b, c) __builtin_amdgcn_mfma_f32_16x16x32_bf16((a), (b), (c), 0, 0, 0)

__device__ __forceinline__ void gload_lds16(const void* g, void* l)
{
    __builtin_amdgcn_global_load_lds(
        (const __attribute__((address_space(1))) unsigned int*)g,
        (__attribute__((address_space(3))) unsigned int*)l, 16, 0, 0);
}

struct LnW { const float* g[2]; const float* b[2]; };

// ---------------------------------------------------------------- casts
__global__ __launch_bounds__(256) void cast_emb_kernel(const float* __restrict__ emb,
                                                       __bf16* __restrict__ A)
{
    int i = (blockIdx.x * 256 + threadIdx.x) * 4;
    int r = i >> 10, d = i & 1023;
    size_t src = ((size_t)(r >> 9) * 1024 + (r & 511)) * 1024 + d;
    f32x4 p = *(const f32x4*)(emb + src);
    f32x4 h = *(const f32x4*)(emb + src + 512 * 1024);
    union { __bf16 b[4]; u16x4 u; } cp, ch;
#pragma unroll
    for (int j = 0; j < 4; ++j) { cp.b[j] = (__bf16)p[j]; ch.b[j] = (__bf16)h[j]; }
    *(u16x4*)(A + i) = cp.u;
    *(u16x4*)(A + 8388608 + i) = ch.u;
}

struct WPtrs { const float* p[8]; };
__global__ __launch_bounds__(256) void cast_wt_kernel(WPtrs wp, __bf16* __restrict__ Wt0)
{
    const float* W = wp.p[blockIdx.z];
    __bf16* Wt = Wt0 + (size_t)blockIdx.z * 1048576;
    __shared__ float tile[32][33];
    int n0 = blockIdx.x * 32, k0 = blockIdx.y * 32;
    int tx = threadIdx.x, ty = threadIdx.y;
#pragma unroll
    for (int i = ty; i < 32; i += 8)
        tile[i][tx] = W[(size_t)(k0 + i) * 1024 + n0 + tx];
    __syncthreads();
#pragma unroll
    for (int i = ty; i < 32; i += 8)
        Wt[(size_t)(n0 + i) * 1024 + k0 + tx] = (__bf16)tile[tx][i];
}

struct GArgs {
    const __bf16* w[2];
    const float* bias[6];
    __bf16* Qb; __bf16* Kb; __bf16* Vt;
    float* Cf; const float* resid;
};

// ---------------------------------------------------------------- QKV GEMM: 256^2 tile,
// 8 waves, BK=64, 2-K-tile LDS double buffer (128 KB), counted-vmcnt phase schedule.
// Grid 768 = 8 xcd * 8 m * 12 n; mblk = xcd*8 + (r&7), nblk = r>>3; dir = mblk>>5;
// seg = n0>>10 (0=Q direct A rows, 1=K / 2=V crossed rows m0^8192).
// Per K-tile: 4 phases x {stage 1 half-tile of kt+1 | ds_read subtile | setprio(1)
// 16 MFMA setprio(0) | s_barrier}. vmcnt(2) + barrier once per K-tile before the
// first read (waits the 8 loads of tile kt, leaves kt+1's 2 newest in flight).
// Swizzle: linear LDS dest + inverse-permuted global source (slot^(row&7));
// reads use the same involution (session-proven since R3; 2 lanes/bank = free).
__global__ __launch_bounds__(512, 2) void gemm256_qkv(const __bf16* __restrict__ A, GArgs a)
{
    __shared__ __align__(16) __bf16 Ab[2][256 * 64];
    __shared__ __align__(16) __bf16 Bb[2][256 * 64];
    const int tid = threadIdx.x, l = tid & 63;
    const int wid = tid >> 6, wm = wid >> 2, wn = wid & 3;
    const int lrow = l & 15, lk = l >> 4;

    const int id = blockIdx.x;
    const int x = id & 7, rr = id >> 3;
    const int mblk = x * 8 + (rr & 7);
    const int nblk = rr >> 3;
    const int m0 = mblk * 256, n0 = nblk * 256;
    const int dir = mblk >> 5;
    const int seg = n0 >> 10;
    const int am0 = (seg != 0) ? (m0 ^ 8192) : m0;
    const __bf16* Ap = A + (size_t)am0 * 1024;
    const __bf16* Bp = a.w[dir] + (size_t)n0 * 1024;

    // stage half-tile hp of K-tile kt into buf b: hp 0,1 = A halves; 2,3 = B halves
    auto stage = [&](int kt, int b, int hp) {
        const __bf16* gp = (hp < 2) ? Ap : Bp;
        __bf16* lp = ((hp < 2) ? Ab[b] : Bb[b]) + (hp & 1) * (128 * 64);
#pragma unroll
        for (int i = 0; i < 2; ++i) {
            int cc = tid + i * 512;
            int rl = cc >> 3, sl = cc & 7;
            int gs = sl ^ (rl & 7);
            gload_lds16(gp + (size_t)((hp & 1) * 128 + rl) * 1024 + kt * 64 + gs * 8,
                        lp + cc * 8);
        }
    };

    // prologue: tile 0 fully issued (8 loads/thread outstanding)
    stage(0, 0, 0); stage(0, 0, 1); stage(0, 0, 2); stage(0, 0, 3);

    const f32x4 zero = {0.f, 0.f, 0.f, 0.f};
    f32x4 acc[8][4];
#pragma unroll
    for (int mi = 0; mi < 8; ++mi)
#pragma unroll
        for (int ni = 0; ni < 4; ++ni) acc[mi][ni] = zero;

    bf16x8 af[4][2], bf[2][2];

    for (int kt = 0; kt < 16; ++kt) {
        const int buf = kt & 1, nbuf = buf ^ 1;
        const __bf16* Abuf = Ab[buf];
        const __bf16* Bbuf = Bb[buf];
        const int arow0 = wm * 128 + lrow;
        const int brow0 = wn * 64 + lrow;

        // ---- phase 0: mi 0-3 x ni 0-1
        if (kt < 15) { stage(kt + 1, nbuf, 0);
                       asm volatile("s_waitcnt vmcnt(2)" ::: "memory"); }
        else         { asm volatile("s_waitcnt vmcnt(0)" ::: "memory"); }
        __builtin_amdgcn_s_barrier();      // all waves' tile-kt loads landed
#pragma unroll
        for (int mi = 0; mi < 4; ++mi) {
            int row = arow0 + mi * 16;
#pragma unroll
            for (int ks = 0; ks < 2; ++ks)
                af[mi][ks] = *(const bf16x8*)(&Abuf[row * 64 + (((ks * 4 + lk) ^ (row & 7)) * 8)]);
        }
#pragma unroll
        for (int ni = 0; ni < 2; ++ni) {
            int row = brow0 + ni * 16;
#pragma unroll
            for (int ks = 0; ks < 2; ++ks)
                bf[ni][ks] = *(const bf16x8*)(&Bbuf[row * 64 + (((ks * 4 + lk) ^ (row & 7)) * 8)]);
        }
        __builtin_amdgcn_s_setprio(1);
#pragma unroll
        for (int mi = 0; mi < 4; ++mi)
#pragma unroll
            for (int ni = 0; ni < 2; ++ni)
#pragma unroll
                for (int ks = 0; ks < 2; ++ks)
                    acc[mi][ni] = MFMA16(af[mi][ks], bf[ni][ks], acc[mi][ni]);
        __builtin_amdgcn_s_setprio(0);
        __builtin_amdgcn_s_barrier();

        // ---- phase 1: mi 0-3 x ni 2-3 (reuse af)
        if (kt < 15) stage(kt + 1, nbuf, 1);
#pragma unroll
        for (int ni = 0; ni < 2; ++ni) {
            int row = brow0 + (ni + 2) * 16;
#pragma unroll
            for (int ks = 0; ks < 2; ++ks)
                bf[ni][ks] = *(const bf16x8*)(&Bbuf[row * 64 + (((ks * 4 + lk) ^ (row & 7)) * 8)]);
        }
        __builtin_amdgcn_s_setprio(1);
#pragma unroll
        for (int mi = 0; mi < 4; ++mi)
#pragma unroll
            for (int ni = 0; ni < 2; ++ni)
#pragma unroll
                for (int ks = 0; ks < 2; ++ks)
                    acc[mi][ni + 2] = MFMA16(af[mi][ks], bf[ni][ks], acc[mi][ni + 2]);
        __builtin_amdgcn_s_setprio(0);
        __builtin_amdgcn_s_barrier();

        // ---- phase 2: mi 4-7 x ni 2-3 (reuse bf)
        if (kt < 15) stage(kt + 1, nbuf, 2);
#pragma unroll
        for (int mi = 0; mi < 4; ++mi) {
            int row = arow0 + (mi + 4) * 16;
#pragma unroll
            for (int ks = 0; ks < 2; ++ks)
                af[mi][ks] = *(const bf16x8*)(&Abuf[row * 64 + (((ks * 4 + lk) ^ (row & 7)) * 8)]);
        }
        __builtin_amdgcn_s_setprio(1);
#pragma unroll
        for (int mi = 0; mi < 4; ++mi)
#pragma unroll
            for (int ni = 0; ni < 2; ++ni)
#pragma unroll
                for (int ks = 0; ks < 2; ++ks)
                    acc[mi + 4][ni + 2] = MFMA16(af[mi][ks], bf[ni][ks], acc[mi + 4][ni + 2]);
        __builtin_amdgcn_s_setprio(0);
        __builtin_amdgcn_s_barrier();

        // ---- phase 3: mi 4-7 x ni 0-1 (reuse af)
        if (kt < 15) stage(kt + 1, nbuf, 3);
#pragma unroll
        for (int ni = 0; ni < 2; ++ni) {
            int row = brow0 + ni * 16;
#pragma unroll
            for (int ks = 0; ks < 2; ++ks)
                bf[ni][ks] = *(const bf16x8*)(&Bbuf[row * 64 + (((ks * 4 + lk) ^ (row & 7)) * 8)]);
        }
        __builtin_amdgcn_s_setprio(1);
#pragma unroll
        for (int mi = 0; mi < 4; ++mi)
#pragma unroll
            for (int ni = 0; ni < 2; ++ni)
#pragma unroll
                for (int ks = 0; ks < 2; ++ks)
                    acc[mi + 4][ni] = MFMA16(af[mi][ks], bf[ni][ks], acc[mi + 4][ni]);
        __builtin_amdgcn_s_setprio(0);
        __builtin_amdgcn_s_barrier();
    }

    const float* bsel = a.bias[dir * 3 + seg];
#pragma unroll
    for (int mi = 0; mi < 8; ++mi) {
#pragma unroll
        for (int ni = 0; ni < 4; ++ni) {
            int col = n0 + wn * 64 + ni * 16 + lrow;
            int c2 = col & 1023;
            float bv = bsel[c2];
#pragma unroll
            for (int r = 0; r < 4; ++r) {
                int row = m0 + wm * 128 + mi * 16 + lk * 4 + r;
                float v = acc[mi][ni][r] + bv;
                if (seg == 0) {
                    a.Qb[(size_t)row * 1024 + c2] = (__bf16)v;
                } else if (seg == 1) {
                    a.Kb[(size_t)row * 1024 + c2] = (__bf16)v;
                } else {
                    int local = row & 8191;
                    int b_ = local >> 9, pos = local & 511;
                    int h_ = c2 >> 6, hd = c2 & 63;
                    a.Vt[(size_t)dir * 8388608 +
                         (((size_t)(b_ * 16 + h_) * 64 + hd) << 9) + pos] = (__bf16)v;
                }
            }
        }
    }
}

// ---------------------------------------------------------------- O GEMM (m97 structure, proven)
// XCD-locality 1-D grid (nwg = 8*16*NN): mblk = (id&7)*16 + ((id>>3)&15), nblk = id>>7.
template <int EPI>
__global__ __launch_bounds__(256, 3) void gemm_bt(const __bf16* __restrict__ A, GArgs a,
                                                  int NN)
{
    __shared__ __align__(16) __bf16 As[128 * 32];
    __shared__ __align__(16) __bf16 Bs[128 * 32];
    const int t = threadIdx.x;
    const int l = t & 63, w = t >> 6;
    const int wr = w >> 1, wc = w & 1;
    const int lrow = l & 15, lk = l >> 4;

    const int id = blockIdx.x;
    const int x = id & 7, rr = id >> 3;
    const int mblk = x * 16 + (rr & 15);
    const int nblk = rr >> 4;
    const int m0 = mblk * 128, n0 = nblk * 128;
    const int dir = mblk >> 6;
    const int r0 = t >> 2, kc0 = (t & 3) * 8;
    const int K = 1024;

    const __bf16* Bt = a.w[dir];
    const __bf16* gA0 = A + (size_t)(m0 + r0) * K + kc0;
    const __bf16* gA1 = gA0 + (size_t)64 * K;
    const __bf16* gB0 = Bt + (size_t)(n0 + r0) * K + kc0;
    const __bf16* gB1 = gB0 + (size_t)64 * K;
    __bf16* dA0 = &As[r0 * 32 + kc0];
    __bf16* dA1 = &As[(r0 + 64) * 32 + kc0];
    __bf16* dB0 = &Bs[r0 * 32 + kc0];
    __bf16* dB1 = &Bs[(r0 + 64) * 32 + kc0];

    const f32x4 zero = {0.f, 0.f, 0.f, 0.f};
    f32x4 acc[4][4];
#pragma unroll
    for (int mi = 0; mi < 4; ++mi)
#pragma unroll
        for (int ni = 0; ni < 4; ++ni) acc[mi][ni] = zero;

    for (int kt = 0; kt < 32; ++kt) {
        const int ko = kt * 32;
        gload_lds16(gA0 + ko, dA0);
        gload_lds16(gA1 + ko, dA1);
        gload_lds16(gB0 + ko, dB0);
        gload_lds16(gB1 + ko, dB1);
        __syncthreads();
        bf16x8 af[4], bfv[4];
#pragma unroll
        for (int mi = 0; mi < 4; ++mi)
            af[mi] = *(const bf16x8*)(&As[(wr * 64 + mi * 16 + lrow) * 32 + lk * 8]);
#pragma unroll
        for (int ni = 0; ni < 4; ++ni)
            bfv[ni] = *(const bf16x8*)(&Bs[(wc * 64 + ni * 16 + lrow) * 32 + lk * 8]);
#pragma unroll
        for (int mi = 0; mi < 4; ++mi)
#pragma unroll
            for (int ni = 0; ni < 4; ++ni)
                acc[mi][ni] = MFMA16(af[mi], bfv[ni], acc[mi][ni]);
        __syncthreads();
    }

#pragma unroll
    for (int mi = 0; mi < 4; ++mi) {
#pragma unroll
        for (int ni = 0; ni < 4; ++ni) {
            int col = n0 + wc * 64 + ni * 16 + lrow;
            int c2 = col & 1023;
            float bv = a.bias[dir * 3][c2];
#pragma unroll
            for (int r = 0; r < 4; ++r) {
                int row = m0 + wr * 64 + mi * 16 + lk * 4 + r;
                float v = acc[mi][ni][r] + bv;
                int local = row & 8191;
                int b_ = local >> 9, s = local & 511;
                float rv = a.resid[((size_t)b_ * 1024 + dir * 512 + s) * 1024 + c2];
                a.Cf[(size_t)row * 1024 + c2] = v + rv;
            }
        }
    }
}

// ---------------------------------------------------------------- attention (R14 proven)
__global__ __launch_bounds__(256, 3) void attn_kernel(const __bf16* __restrict__ Q,
                                                      const __bf16* __restrict__ Kb,
                                                      const __bf16* __restrict__ Vt,
                                                      const float* __restrict__ mask,
                                                      __bf16* __restrict__ att)
{
    __shared__ __align__(16) __bf16 KB[2][128 * 64];
    __shared__ __align__(16) __bf16 Pt[64 * 128];
    __shared__ __align__(16) float msk[512];
    const int id = blockIdx.x;
    const int xcd = id & 7, slot = id >> 3;
    const int dirbh = xcd * 64 + (slot >> 3);
    const int q0 = (slot & 7) * 64;
    const int dir = dirbh >> 8, bh = dirbh & 255;
    const int b = bh >> 4, h = bh & 15;
    const int mask_half = dir ? 0 : 512;
    const int tid = threadIdx.x, l = tid & 63, w = tid >> 6;
    const int lrow = l & 15, lk = l >> 4;
    const size_t rowbase = (size_t)dir * 8192 + b * 512;

    const __bf16* kbase = Kb + rowbase * 1024 + h * 64;
    const __bf16* vsrc = Vt + (size_t)dir * 8388608 + (size_t)bh * 64 * 512;

    auto stage = [&](int t, int buf) {
        char* dst = (char*)KB[buf];
#pragma unroll
        for (int i = 0; i < 4; ++i) {
            int c = tid + i * 256;
            int pos = c >> 3, gslot = (c & 7) ^ (pos & 7);
            gload_lds16(kbase + (size_t)(t * 128 + pos) * 1024 + gslot * 8, dst + c * 16);
        }
    };

    stage(0, 0);
    for (int i = tid; i < 512; i += 256) msk[i] = mask[b * 1024 + mask_half + i];

    const __bf16* qptr = Q + (rowbase + q0 + w * 16 + lrow) * 1024 + h * 64;
    bf16x8 qf0 = *(const bf16x8*)(qptr + lk * 8);
    bf16x8 qf1 = *(const bf16x8*)(qptr + 32 + lk * 8);

    const f32x4 zero = {0.f, 0.f, 0.f, 0.f};
    f32x4 av[4];
#pragma unroll
    for (int ni = 0; ni < 4; ++ni) av[ni] = zero;
    float m_run = -3e38f, su = 0.f;
    const int psw = lrow & 7;
    char* prowp = (char*)Pt + (w * 16 + lrow) * 256;
    f32x4 sc[8];
    bf16x8 vfr[16];

#pragma unroll
    for (int t = 0; t < 4; ++t) {
        __syncthreads();
        const char* kbuf = (const char*)KB[t & 1];
#pragma unroll
        for (int jj = 0; jj < 8; ++jj) {
            const char* kb = kbuf + (jj * 16 + lrow) * 128;
            bf16x8 k0 = *(const bf16x8*)(kb + ((lk ^ psw) << 4));
            bf16x8 k1 = *(const bf16x8*)(kb + (((lk + 4) ^ psw) << 4));
            f32x4 c = zero;
            c = MFMA16(k0, qf0, c);
            c = MFMA16(k1, qf1, c);
            sc[jj] = c;
        }
        if (t < 3) stage(t + 1, (t + 1) & 1);

        const int koff = t * 128;
#pragma unroll
        for (int ks = 0; ks < 4; ++ks)
#pragma unroll
            for (int ni = 0; ni < 4; ++ni)
                vfr[ks * 4 + ni] =
                    *(const bf16x8*)(&vsrc[(ni * 16 + lrow) * 512 + koff + ks * 32 + lk * 8]);

        float mt = -3e38f;
#pragma unroll
        for (int jj = 0; jj < 8; ++jj) {
            f32x4 mv = *(const f32x4*)(&msk[koff + jj * 16 + lk * 4]);
#pragma unroll
            for (int r = 0; r < 4; ++r) {
                float s = sc[jj][r] * 0.125f;
                if (mv[r] == 0.f) s = -1e9f;
                sc[jj][r] = s;
                mt = fmaxf(mt, s);
            }
        }
        mt = fmaxf(mt, __shfl_xor(mt, 16));
        mt = fmaxf(mt, __shfl_xor(mt, 32));
        float m_new = fmaxf(m_run, mt);
        float f = __expf(m_run - m_new);
        float s0 = 0.f, s1 = 0.f;
#pragma unroll
        for (int jj = 0; jj < 8; ++jj) {
            float e0 = __expf(sc[jj][0] - m_new);
            float e1 = __expf(sc[jj][1] - m_new);
            float e2 = __expf(sc[jj][2] - m_new);
            float e3 = __expf(sc[jj][3] - m_new);
            sc[jj][0] = e0; sc[jj][1] = e1; sc[jj][2] = e2; sc[jj][3] = e3;
            s0 += e0 + e1;
            s1 += e2 + e3;
        }
        float ssum = s0 + s1;
        ssum += __shfl_xor(ssum, 16);
        ssum += __shfl_xor(ssum, 32);
        su = su * f + ssum;
        m_run = m_new;
#pragma unroll
        for (int r = 0; r < 4; ++r) {
            float fr = __shfl(f, (l & 48) | (lk * 4 + r));
#pragma unroll
            for (int ni = 0; ni < 4; ++ni) av[ni][r] *= fr;
        }

#pragma unroll
        for (int jj = 0; jj < 8; ++jj) {
            union { __bf16 b[4]; unsigned long long u; } pk;
#pragma unroll
            for (int r = 0; r < 4; ++r) pk.b[r] = (__bf16)sc[jj][r];
            int slot2 = jj * 2 + (lk >> 1);
            *(unsigned long long*)(prowp + (((slot2 ^ psw) << 4) | ((lk & 1) << 3))) = pk.u;
        }
#pragma unroll
        for (int ks = 0; ks < 4; ++ks) {
            bf16x8 pf = *(const bf16x8*)(prowp + (((ks * 4 + lk) ^ psw) << 4));
#pragma unroll
            for (int ni = 0; ni < 4; ++ni)
                av[ni] = MFMA16(pf, vfr[ks * 4 + ni], av[ni]);
        }
    }

    const float inv = 1.f / su;
#pragma unroll
    for (int r = 0; r < 4; ++r) {
        float ivr = __shfl(inv, (l & 48) | (lk * 4 + r));
        size_t orow = rowbase + q0 + w * 16 + lk * 4 + r;
#pragma unroll
        for (int ni = 0; ni < 4; ++ni)
            att[orow * 1024 + h * 64 + ni * 16 + lrow] = (__bf16)(av[ni][r] * ivr);
    }
}

// ---------------------------------------------------------------- LN stats
__global__ __launch_bounds__(256) void ln_stats_kernel(const float* __restrict__ X,
                                                       float2* __restrict__ stats)
{
    const int r = blockIdx.x, t = threadIdx.x;
    const float* x = X + (size_t)r * 1024;
    f32x4 v = *(const f32x4*)(x + t * 4);
    float s = v[0] + v[1] + v[2] + v[3];
    float q = v[0] * v[0] + v[1] * v[1] + v[2] * v[2] + v[3] * v[3];
#pragma unroll
    for (int d = 1; d < 64; d <<= 1) { s += __shfl_xor(s, d); q += __shfl_xor(q, d); }
    __shared__ float rs[4], rq[4];
    if ((t & 63) == 0) { rs[t >> 6] = s; rq[t >> 6] = q; }
    __syncthreads();
    if (t == 0) {
        s = rs[0] + rs[1] + rs[2] + rs[3];
        q = rq[0] + rq[1] + rq[2] + rq[3];
        float mu = s * (1.f / 1024.f);
        float var = q * (1.f / 1024.f) - mu * mu;
        stats[r] = make_float2(mu, rsqrtf(var + 1e-5f));
    }
}

// ---------------------------------------------------------------- pools
__global__ __launch_bounds__(256) void pool_f32_kernel(const float* __restrict__ X,
                                                       const float* __restrict__ mask,
                                                       float* __restrict__ feats)
{
    const int b = blockIdx.y, d0 = blockIdx.x * 64, half = blockIdx.z * 512;
    const int t = threadIdx.x, d = d0 + (t & 63), sl = t >> 6;
    float acc = 0.f, ms = 0.f;
#pragma unroll 4
    for (int s = sl * 128; s < sl * 128 + 128; ++s) {
        float m = mask[b * 1024 + half + s];
        acc += X[((size_t)b * 1024 + half + s) * 1024 + d] * m;
        ms += m;
    }
    __shared__ float ra[4][64];
    __shared__ float rm[4];
    ra[sl][t & 63] = acc;
    if ((t & 63) == 0) rm[sl] = ms;
    __syncthreads();
    if (t < 64) {
        float a = ra[0][t] + ra[1][t] + ra[2][t] + ra[3][t];
        float m = rm[0] + rm[1] + rm[2] + rm[3];
        feats[b * 4096 + blockIdx.z * 1024 + d0 + t] = a / fmaxf(m, 1e-9f);
    }
}

__global__ __launch_bounds__(256) void pool_ln_kernel(const float* __restrict__ Of,
                                                      const float2* __restrict__ stats,
                                                      const float* __restrict__ mask,
                                                      LnW lw,
                                                      float* __restrict__ feats)
{
    const int b = blockIdx.y, d0 = blockIdx.x * 64, dir = blockIdx.z;
    const int half = dir * 512;
    const int t = threadIdx.x, d = d0 + (t & 63), sl = t >> 6;
    float acc = 0.f, ms = 0.f;
#pragma unroll 4
    for (int s = sl * 128; s < sl * 128 + 128; ++s) {
        float m = mask[b * 1024 + half + s];
        int row = dir * 8192 + b * 512 + s;
        float2 st = stats[row];
        float x = Of[(size_t)row * 1024 + d];
        acc += m * (x - st.x) * st.y;
        ms += m;
    }
    __shared__ float ra[4][64];
    __shared__ float rm[4];
    ra[sl][t & 63] = acc;
    if ((t & 63) == 0) rm[sl] = ms;
    __syncthreads();
    if (t < 64) {
        float a = ra[0][t] + ra[1][t] + ra[2][t] + ra[3][t];
        float m = rm[0] + rm[1] + rm[2] + rm[3];
        float g = lw.g[dir][d0 + t], bb = lw.b[dir][d0 + t];
        feats[b * 4096 + 2048 + dir * 1024 + d0 + t] = (g * a + bb * m) / fmaxf(m, 1e-9f);
    }
}

// ---------------------------------------------------------------- small fp32 MLP
__global__ __launch_bounds__(256) void fc_init_kernel(const float* __restrict__ b1,
                                                      const float* __restrict__ b2,
                                                      float* __restrict__ h1,
                                                      float* __restrict__ h2)
{
    int i = blockIdx.x * 256 + threadIdx.x;
    if (i < 16 * 1024) h1[i] = b1[i & 1023];
    else h2[i - 16 * 1024] = b2[(i - 16 * 1024) & 511];
}

template <int CH, int RELU_IN>
__global__ __launch_bounds__(256) void fc_atomic_kernel(const float* __restrict__ in,
                                                        const float* __restrict__ W,
                                                        float* __restrict__ out,
                                                        int IF, int OF)
{
    __shared__ float ins[16 * CH];
    const int t = threadIdx.x;
    const int col = blockIdx.x * 256 + t;
    const int i0 = blockIdx.y * CH;
#pragma unroll
    for (int idx = t; idx < 16 * CH; idx += 256) {
        int b = idx / CH, i = idx % CH;
        float v = in[b * IF + i0 + i];
        if (RELU_IN) v = fmaxf(v, 0.f);
        ins[idx] = v;
    }
    __syncthreads();
    float acc[16];
#pragma unroll
    for (int b = 0; b < 16; ++b) acc[b] = 0.f;
#pragma unroll 4
    for (int i = 0; i < CH; ++i) {
        float wv = W[(size_t)(i0 + i) * OF + col];
#pragma unroll
        for (int b = 0; b < 16; ++b) acc[b] += ins[b * CH + i] * wv;
    }
#pragma unroll
    for (int b = 0; b < 16; ++b) atomicAdd(out + b * OF + col, acc[b]);
}

__global__ __launch_bounds__(64) void mlp3_kernel(const float* __restrict__ h2,
                                                  const float* __restrict__ W3,
                                                  const float* __restrict__ b3,
                                                  float* __restrict__ out)
{
    int b = blockIdx.x, t = threadIdx.x;
    float a0 = 0.f, a1 = 0.f, a2 = 0.f;
    for (int i = t; i < 512; i += 64) {
        float hv = fmaxf(h2[b * 512 + i], 0.f);
        a0 += hv * W3[i * 3 + 0];
        a1 += hv * W3[i * 3 + 1];
        a2 += hv * W3[i * 3 + 2];
    }
#pragma unroll
    for (int d = 1; d < 64; d <<= 1) {
        a0 += __shfl_xor(a0, d);
        a1 += __shfl_xor(a1, d);
        a2 += __shfl_xor(a2, d);
    }
    if (t == 0) {
        out[b * 3 + 0] = a0 + b3[0];
        out[b * 3 + 1] = a1 + b3[1];
        out[b * 3 + 2] = a2 + b3[2];
    }
}

// ---------------------------------------------------------------- launch
extern "C" void kernel_launch(void* const* d_in, const int* in_sizes, int n_in,
                              void* d_out, int out_size, void* d_ws, size_t ws_size,
                              hipStream_t stream)
{
    const float* emb  = (const float*)d_in[0];
    const float* mask = (const float*)d_in[1];
    const float* W1 = (const float*)d_in[22];
    const float* b1 = (const float*)d_in[23];
    const float* W2 = (const float*)d_in[24];
    const float* b2 = (const float*)d_in[25];
    const float* W3 = (const float*)d_in[26];
    const float* b3 = (const float*)d_in[27];

    char* ws = (char*)d_ws;
    constexpr size_t MB = 1ull << 20;
    __bf16* A     = (__bf16*)(ws);
    __bf16* Wt    = (__bf16*)(ws + 32 * MB);
    __bf16* Qb    = (__bf16*)(ws + 48 * MB);
    __bf16* Kb    = (__bf16*)(ws + 80 * MB);
    __bf16* Vt    = (__bf16*)(ws + 112 * MB);
    __bf16* attb  = (__bf16*)(ws);                 // alias A
    float*  Of    = (float*) (ws + 48 * MB);       // alias Qb+Kb
    float*  feats = (float*) (ws + 144 * MB);
    float*  h1    = (float*) (ws + 144 * MB + 512 * 1024);
    float*  h2    = (float*) (ws + 145 * MB);
    float2* stats = (float2*)(ws + 146 * MB);

    cast_emb_kernel<<<8192, 256, 0, stream>>>(emb, A);
    WPtrs wp;
    const int widx[8] = {2, 4, 6, 8, 12, 14, 16, 18};
    for (int i = 0; i < 8; ++i) wp.p[i] = (const float*)d_in[widx[i]];
    cast_wt_kernel<<<dim3(32, 32, 8), dim3(32, 8), 0, stream>>>(wp, Wt);

    GArgs gqkv = {}, go = {};
    LnW lw;
    for (int dir = 0; dir < 2; ++dir) {
        const int base = dir ? 12 : 2;
        gqkv.w[dir] = Wt + (size_t)(dir * 4) * 1048576;
        gqkv.bias[dir * 3 + 0] = (const float*)d_in[base + 1];
        gqkv.bias[dir * 3 + 1] = (const float*)d_in[base + 3];
        gqkv.bias[dir * 3 + 2] = (const float*)d_in[base + 5];
        go.w[dir] = Wt + (size_t)(dir * 4 + 3) * 1048576;
        go.bias[dir * 3] = (const float*)d_in[base + 7];
        lw.g[dir] = (const float*)d_in[base + 8];
        lw.b[dir] = (const float*)d_in[base + 9];
    }
    gqkv.Qb = Qb; gqkv.Kb = Kb; gqkv.Vt = Vt;
    go.Cf = Of; go.resid = emb;

    // QKV: 256^2-tile phased kernel; 768 WGs = 8 xcd * 8 m * 12 n
    gemm256_qkv<<<768, 512, 0, stream>>>(A, gqkv);
    attn_kernel<<<4096, 256, 0, stream>>>(Qb, Kb, Vt, mask, attb);
    gemm_bt<2><<<1024, 256, 0, stream>>>(attb, go, 8);
    ln_stats_kernel<<<16384, 256, 0, stream>>>(Of, stats);
    pool_ln_kernel<<<dim3(16, 16, 2), 256, 0, stream>>>(Of, stats, mask, lw, feats);
    pool_f32_kernel<<<dim3(16, 16, 2), 256, 0, stream>>>(emb, mask, feats);

    fc_init_kernel<<<96, 256, 0, stream>>>(b1, b2, h1, h2);
    fc_atomic_kernel<128, 0><<<dim3(4, 32), 256, 0, stream>>>(feats, W1, h1, 4096, 1024);
    fc_atomic_kernel<32, 1><<<dim3(2, 32), 256, 0, stream>>>(h1, W2, h2, 1024, 512);
    mlp3_kernel<<<16, 64, 0, stream>>>(h2, W3, b3, (float*)d_out);
}

// Round 16
// 497.816 us; speedup vs baseline: 1.0697x; 1.0697x over previous
//
#include <hip/hip_runtime.h>
#include <hip/hip_bf16.h>

typedef __attribute__((ext_vector_type(8))) __bf16 bf16x8;
typedef __attribute__((ext_vector_type(4))) float f32x4;
typedef __attribute__((ext_vector_type(4))) int i32x4;
typedef __attribute__((ext_vector_type(4))) unsigned short u16x4;

#define MFMA16(a, b, c) __builtin_amdgcn_mfma_f32_16x16x32_bf16((a), (b), (c), 0, 0, 0)

__device__ __forceinline__ void gload_lds16(const void* g, void* l)
{
    __builtin_amdgcn_global_load_lds(
        (const __attribute__((address_space(1))) unsigned int*)g,
        (__attribute__((address_space(3))) unsigned int*)l, 16, 0, 0);
}

struct LnW { const float* g[2]; const float* b[2]; };

// ---------------------------------------------------------------- casts
__global__ __launch_bounds__(256) void cast_emb_kernel(const float* __restrict__ emb,
                                                       __bf16* __restrict__ A)
{
    int i = (blockIdx.x * 256 + threadIdx.x) * 4;
    int r = i >> 10, d = i & 1023;
    size_t src = ((size_t)(r >> 9) * 1024 + (r & 511)) * 1024 + d;
    f32x4 p = *(const f32x4*)(emb + src);
    f32x4 h = *(const f32x4*)(emb + src + 512 * 1024);
    union { __bf16 b[4]; u16x4 u; } cp, ch;
#pragma unroll
    for (int j = 0; j < 4; ++j) { cp.b[j] = (__bf16)p[j]; ch.b[j] = (__bf16)h[j]; }
    *(u16x4*)(A + i) = cp.u;
    *(u16x4*)(A + 8388608 + i) = ch.u;
}

struct WPtrs { const float* p[8]; };
__global__ __launch_bounds__(256) void cast_wt_kernel(WPtrs wp, __bf16* __restrict__ Wt0)
{
    const float* W = wp.p[blockIdx.z];
    __bf16* Wt = Wt0 + (size_t)blockIdx.z * 1048576;
    __shared__ float tile[32][33];
    int n0 = blockIdx.x * 32, k0 = blockIdx.y * 32;
    int tx = threadIdx.x, ty = threadIdx.y;
#pragma unroll
    for (int i = ty; i < 32; i += 8)
        tile[i][tx] = W[(size_t)(k0 + i) * 1024 + n0 + tx];
    __syncthreads();
#pragma unroll
    for (int i = ty; i < 32; i += 8)
        Wt[(size_t)(n0 + i) * 1024 + k0 + tx] = (__bf16)tile[tx][i];
}

// ---------------------------------------------------------------- GEMM (m97 structure, proven)
// Merged 2-direction GEMM, M=16384 (128 m-panels), dir = mblk>>6.
// XCD-locality 1-D grid (nwg = 8*16*NN): x=id&7, r=id>>3, mm=r&15, n=r>>4,
// mblk = x*16+mm. XCD x owns m-panels [16x,16x+16) -> A stays L2-resident.
// [R12 verified: QKV FETCH 310 -> 81 MB. R15's 256^2 phased port regressed
//  (173 vs 156 us, MfmaUtil 23.6 vs 28.4, 1 blk/CU lockstep) -> reverted.]
// EPI 5 (QKV): NN=24, seg = n0>>10: 0=Q (A rows direct), 1=K, 2=V (rows ^8192).
// EPI 2 (O):   NN=8; Cf = v + resid; fused LN-stats partial sums via
//              lrow-shfl reduce + 1 atomicAdd per (row,wave) (saves the
//              16384-block ln_stats re-read of Of).
struct GArgs {
    const __bf16* w[2];
    const float* bias[6];
    __bf16* Qb; __bf16* Kb; __bf16* Vt;
    float* Cf; const float* resid;
    float* ssum; float* sqsum;
};
template <int EPI>
__global__ __launch_bounds__(256, 3) void gemm_bt(const __bf16* __restrict__ A, GArgs a,
                                                  int NN)
{
    __shared__ __align__(16) __bf16 As[128 * 32];
    __shared__ __align__(16) __bf16 Bs[128 * 32];
    const int t = threadIdx.x;
    const int l = t & 63, w = t >> 6;
    const int wr = w >> 1, wc = w & 1;
    const int lrow = l & 15, lk = l >> 4;

    const int id = blockIdx.x;
    const int x = id & 7, rr = id >> 3;
    const int mblk = x * 16 + (rr & 15);
    const int nblk = rr >> 4;
    const int m0 = mblk * 128, n0 = nblk * 128;
    const int dir = mblk >> 6;
    const int seg = (EPI == 5) ? (n0 >> 10) : 0;
    const int r0 = t >> 2, kc0 = (t & 3) * 8;
    const int K = 1024;

    const int am0 = (EPI == 5 && seg != 0) ? (m0 ^ 8192) : m0;
    const __bf16* Bt = a.w[dir];
    const __bf16* gA0 = A + (size_t)(am0 + r0) * K + kc0;
    const __bf16* gA1 = gA0 + (size_t)64 * K;
    const __bf16* gB0 = Bt + (size_t)(n0 + r0) * K + kc0;
    const __bf16* gB1 = gB0 + (size_t)64 * K;
    __bf16* dA0 = &As[r0 * 32 + kc0];
    __bf16* dA1 = &As[(r0 + 64) * 32 + kc0];
    __bf16* dB0 = &Bs[r0 * 32 + kc0];
    __bf16* dB1 = &Bs[(r0 + 64) * 32 + kc0];

    const f32x4 zero = {0.f, 0.f, 0.f, 0.f};
    f32x4 acc[4][4];
#pragma unroll
    for (int mi = 0; mi < 4; ++mi)
#pragma unroll
        for (int ni = 0; ni < 4; ++ni) acc[mi][ni] = zero;

    for (int kt = 0; kt < 32; ++kt) {
        const int ko = kt * 32;
        gload_lds16(gA0 + ko, dA0);
        gload_lds16(gA1 + ko, dA1);
        gload_lds16(gB0 + ko, dB0);
        gload_lds16(gB1 + ko, dB1);
        __syncthreads();
        bf16x8 af[4], bfv[4];
#pragma unroll
        for (int mi = 0; mi < 4; ++mi)
            af[mi] = *(const bf16x8*)(&As[(wr * 64 + mi * 16 + lrow) * 32 + lk * 8]);
#pragma unroll
        for (int ni = 0; ni < 4; ++ni)
            bfv[ni] = *(const bf16x8*)(&Bs[(wc * 64 + ni * 16 + lrow) * 32 + lk * 8]);
#pragma unroll
        for (int mi = 0; mi < 4; ++mi)
#pragma unroll
            for (int ni = 0; ni < 4; ++ni)
                acc[mi][ni] = MFMA16(af[mi], bfv[ni], acc[mi][ni]);
        __syncthreads();
    }

    float rs_[4][4], rq_[4][4];
    if (EPI == 2) {
#pragma unroll
        for (int mi = 0; mi < 4; ++mi)
#pragma unroll
            for (int r = 0; r < 4; ++r) { rs_[mi][r] = 0.f; rq_[mi][r] = 0.f; }
    }

    const float* bsel = a.bias[dir * 3 + seg];
#pragma unroll
    for (int mi = 0; mi < 4; ++mi) {
#pragma unroll
        for (int ni = 0; ni < 4; ++ni) {
            int col = n0 + wc * 64 + ni * 16 + lrow;
            int c2 = col & 1023;
            float bv = bsel[c2];
#pragma unroll
            for (int r = 0; r < 4; ++r) {
                int row = m0 + wr * 64 + mi * 16 + lk * 4 + r;
                float v = acc[mi][ni][r] + bv;
                if (EPI == 5) {
                    if (seg == 0) {
                        a.Qb[(size_t)row * 1024 + c2] = (__bf16)v;
                    } else if (seg == 1) {
                        a.Kb[(size_t)row * 1024 + c2] = (__bf16)v;
                    } else {
                        int local = row & 8191;
                        int b_ = local >> 9, pos = local & 511;
                        int h_ = c2 >> 6, hd = c2 & 63;
                        a.Vt[(size_t)dir * 8388608 +
                             (((size_t)(b_ * 16 + h_) * 64 + hd) << 9) + pos] = (__bf16)v;
                    }
                } else {
                    int local = row & 8191;
                    int b_ = local >> 9, s = local & 511;
                    float rv = a.resid[((size_t)b_ * 1024 + dir * 512 + s) * 1024 + c2];
                    float ov = v + rv;
                    a.Cf[(size_t)row * 1024 + c2] = ov;
                    rs_[mi][r] += ov;
                    rq_[mi][r] += ov * ov;
                }
            }
        }
    }

    if (EPI == 2) {
        // LN partial sums: rows depend on (mi,lk,r), not lrow -> reduce across the
        // 16-lane lrow group, then one atomicAdd per (row, wave).
#pragma unroll
        for (int mi = 0; mi < 4; ++mi)
#pragma unroll
            for (int r = 0; r < 4; ++r) {
                float s = rs_[mi][r], q = rq_[mi][r];
#pragma unroll
                for (int d = 1; d < 16; d <<= 1) {
                    s += __shfl_xor(s, d);
                    q += __shfl_xor(q, d);
                }
                if (lrow == 0) {
                    int row = m0 + wr * 64 + mi * 16 + lk * 4 + r;
                    atomicAdd(a.ssum + row, s);
                    atomicAdd(a.sqsum + row, q);
                }
            }
    }
}

// ---------------------------------------------------------------- attention (R14 proven)
__global__ __launch_bounds__(256, 3) void attn_kernel(const __bf16* __restrict__ Q,
                                                      const __bf16* __restrict__ Kb,
                                                      const __bf16* __restrict__ Vt,
                                                      const float* __restrict__ mask,
                                                      __bf16* __restrict__ att)
{
    __shared__ __align__(16) __bf16 KB[2][128 * 64];
    __shared__ __align__(16) __bf16 Pt[64 * 128];
    __shared__ __align__(16) float msk[512];
    const int id = blockIdx.x;
    const int xcd = id & 7, slot = id >> 3;
    const int dirbh = xcd * 64 + (slot >> 3);
    const int q0 = (slot & 7) * 64;
    const int dir = dirbh >> 8, bh = dirbh & 255;
    const int b = bh >> 4, h = bh & 15;
    const int mask_half = dir ? 0 : 512;
    const int tid = threadIdx.x, l = tid & 63, w = tid >> 6;
    const int lrow = l & 15, lk = l >> 4;
    const size_t rowbase = (size_t)dir * 8192 + b * 512;

    const __bf16* kbase = Kb + rowbase * 1024 + h * 64;
    const __bf16* vsrc = Vt + (size_t)dir * 8388608 + (size_t)bh * 64 * 512;

    auto stage = [&](int t, int buf) {
        char* dst = (char*)KB[buf];
#pragma unroll
        for (int i = 0; i < 4; ++i) {
            int c = tid + i * 256;
            int pos = c >> 3, gslot = (c & 7) ^ (pos & 7);
            gload_lds16(kbase + (size_t)(t * 128 + pos) * 1024 + gslot * 8, dst + c * 16);
        }
    };

    stage(0, 0);
    for (int i = tid; i < 512; i += 256) msk[i] = mask[b * 1024 + mask_half + i];

    const __bf16* qptr = Q + (rowbase + q0 + w * 16 + lrow) * 1024 + h * 64;
    bf16x8 qf0 = *(const bf16x8*)(qptr + lk * 8);
    bf16x8 qf1 = *(const bf16x8*)(qptr + 32 + lk * 8);

    const f32x4 zero = {0.f, 0.f, 0.f, 0.f};
    f32x4 av[4];
#pragma unroll
    for (int ni = 0; ni < 4; ++ni) av[ni] = zero;
    float m_run = -3e38f, su = 0.f;
    const int psw = lrow & 7;
    char* prowp = (char*)Pt + (w * 16 + lrow) * 256;
    f32x4 sc[8];
    bf16x8 vfr[16];

#pragma unroll
    for (int t = 0; t < 4; ++t) {
        __syncthreads();
        const char* kbuf = (const char*)KB[t & 1];
#pragma unroll
        for (int jj = 0; jj < 8; ++jj) {
            const char* kb = kbuf + (jj * 16 + lrow) * 128;
            bf16x8 k0 = *(const bf16x8*)(kb + ((lk ^ psw) << 4));
            bf16x8 k1 = *(const bf16x8*)(kb + (((lk + 4) ^ psw) << 4));
            f32x4 c = zero;
            c = MFMA16(k0, qf0, c);
            c = MFMA16(k1, qf1, c);
            sc[jj] = c;
        }
        if (t < 3) stage(t + 1, (t + 1) & 1);

        const int koff = t * 128;
#pragma unroll
        for (int ks = 0; ks < 4; ++ks)
#pragma unroll
            for (int ni = 0; ni < 4; ++ni)
                vfr[ks * 4 + ni] =
                    *(const bf16x8*)(&vsrc[(ni * 16 + lrow) * 512 + koff + ks * 32 + lk * 8]);

        float mt = -3e38f;
#pragma unroll
        for (int jj = 0; jj < 8; ++jj) {
            f32x4 mv = *(const f32x4*)(&msk[koff + jj * 16 + lk * 4]);
#pragma unroll
            for (int r = 0; r < 4; ++r) {
                float s = sc[jj][r] * 0.125f;
                if (mv[r] == 0.f) s = -1e9f;
                sc[jj][r] = s;
                mt = fmaxf(mt, s);
            }
        }
        mt = fmaxf(mt, __shfl_xor(mt, 16));
        mt = fmaxf(mt, __shfl_xor(mt, 32));
        float m_new = fmaxf(m_run, mt);
        float f = __expf(m_run - m_new);
        float s0 = 0.f, s1 = 0.f;
#pragma unroll
        for (int jj = 0; jj < 8; ++jj) {
            float e0 = __expf(sc[jj][0] - m_new);
            float e1 = __expf(sc[jj][1] - m_new);
            float e2 = __expf(sc[jj][2] - m_new);
            float e3 = __expf(sc[jj][3] - m_new);
            sc[jj][0] = e0; sc[jj][1] = e1; sc[jj][2] = e2; sc[jj][3] = e3;
            s0 += e0 + e1;
            s1 += e2 + e3;
        }
        float ssum = s0 + s1;
        ssum += __shfl_xor(ssum, 16);
        ssum += __shfl_xor(ssum, 32);
        su = su * f + ssum;
        m_run = m_new;
#pragma unroll
        for (int r = 0; r < 4; ++r) {
            float fr = __shfl(f, (l & 48) | (lk * 4 + r));
#pragma unroll
            for (int ni = 0; ni < 4; ++ni) av[ni][r] *= fr;
        }

#pragma unroll
        for (int jj = 0; jj < 8; ++jj) {
            union { __bf16 b[4]; unsigned long long u; } pk;
#pragma unroll
            for (int r = 0; r < 4; ++r) pk.b[r] = (__bf16)sc[jj][r];
            int slot2 = jj * 2 + (lk >> 1);
            *(unsigned long long*)(prowp + (((slot2 ^ psw) << 4) | ((lk & 1) << 3))) = pk.u;
        }
#pragma unroll
        for (int ks = 0; ks < 4; ++ks) {
            bf16x8 pf = *(const bf16x8*)(prowp + (((ks * 4 + lk) ^ psw) << 4));
#pragma unroll
            for (int ni = 0; ni < 4; ++ni)
                av[ni] = MFMA16(pf, vfr[ks * 4 + ni], av[ni]);
        }
    }

    const float inv = 1.f / su;
#pragma unroll
    for (int r = 0; r < 4; ++r) {
        float ivr = __shfl(inv, (l & 48) | (lk * 4 + r));
        size_t orow = rowbase + q0 + w * 16 + lk * 4 + r;
#pragma unroll
        for (int ni = 0; ni < 4; ++ni)
            att[orow * 1024 + h * 64 + ni * 16 + lrow] = (__bf16)(av[ni][r] * ivr);
    }
}

// ---------------------------------------------------------------- LN finalize (from atomic sums)
__global__ __launch_bounds__(256) void ln_finalize_kernel(const float* __restrict__ ssum,
                                                          const float* __restrict__ sqsum,
                                                          float2* __restrict__ stats)
{
    int r = blockIdx.x * 256 + threadIdx.x;
    float mu = ssum[r] * (1.f / 1024.f);
    float var = sqsum[r] * (1.f / 1024.f) - mu * mu;
    stats[r] = make_float2(mu, rsqrtf(var + 1e-5f));
}

// ---------------------------------------------------------------- pools
__global__ __launch_bounds__(256) void pool_f32_kernel(const float* __restrict__ X,
                                                       const float* __restrict__ mask,
                                                       float* __restrict__ feats)
{
    const int b = blockIdx.y, d0 = blockIdx.x * 64, half = blockIdx.z * 512;
    const int t = threadIdx.x, d = d0 + (t & 63), sl = t >> 6;
    float acc = 0.f, ms = 0.f;
#pragma unroll 4
    for (int s = sl * 128; s < sl * 128 + 128; ++s) {
        float m = mask[b * 1024 + half + s];
        acc += X[((size_t)b * 1024 + half + s) * 1024 + d] * m;
        ms += m;
    }
    __shared__ float ra[4][64];
    __shared__ float rm[4];
    ra[sl][t & 63] = acc;
    if ((t & 63) == 0) rm[sl] = ms;
    __syncthreads();
    if (t < 64) {
        float a = ra[0][t] + ra[1][t] + ra[2][t] + ra[3][t];
        float m = rm[0] + rm[1] + rm[2] + rm[3];
        feats[b * 4096 + blockIdx.z * 1024 + d0 + t] = a / fmaxf(m, 1e-9f);
    }
}

__global__ __launch_bounds__(256) void pool_ln_kernel(const float* __restrict__ Of,
                                                      const float2* __restrict__ stats,
                                                      const float* __restrict__ mask,
                                                      LnW lw,
                                                      float* __restrict__ feats)
{
    const int b = blockIdx.y, d0 = blockIdx.x * 64, dir = blockIdx.z;
    const int half = dir * 512;
    const int t = threadIdx.x, d = d0 + (t & 63), sl = t >> 6;
    float acc = 0.f, ms = 0.f;
#pragma unroll 4
    for (int s = sl * 128; s < sl * 128 + 128; ++s) {
        float m = mask[b * 1024 + half + s];
        int row = dir * 8192 + b * 512 + s;
        float2 st = stats[row];
        float x = Of[(size_t)row * 1024 + d];
        acc += m * (x - st.x) * st.y;
        ms += m;
    }
    __shared__ float ra[4][64];
    __shared__ float rm[4];
    ra[sl][t & 63] = acc;
    if ((t & 63) == 0) rm[sl] = ms;
    __syncthreads();
    if (t < 64) {
        float a = ra[0][t] + ra[1][t] + ra[2][t] + ra[3][t];
        float m = rm[0] + rm[1] + rm[2] + rm[3];
        float g = lw.g[dir][d0 + t], bb = lw.b[dir][d0 + t];
        feats[b * 4096 + 2048 + dir * 1024 + d0 + t] = (g * a + bb * m) / fmaxf(m, 1e-9f);
    }
}

// ---------------------------------------------------------------- small fp32 MLP + zero-init
// i<16384: h1 <- b1; i<24576: h2 <- b2; rest: zero ssum|sqsum (32768 floats)
__global__ __launch_bounds__(256) void fc_init_kernel(const float* __restrict__ b1,
                                                      const float* __restrict__ b2,
                                                      float* __restrict__ h1,
                                                      float* __restrict__ h2,
                                                      float* __restrict__ zeros)
{
    int i = blockIdx.x * 256 + threadIdx.x;
    if (i < 16384) h1[i] = b1[i & 1023];
    else if (i < 24576) h2[i - 16384] = b2[(i - 16384) & 511];
    else zeros[i - 24576] = 0.f;
}

template <int CH, int RELU_IN>
__global__ __launch_bounds__(256) void fc_atomic_kernel(const float* __restrict__ in,
                                                        const float* __restrict__ W,
                                                        float* __restrict__ out,
                                                        int IF, int OF)
{
    __shared__ float ins[16 * CH];
    const int t = threadIdx.x;
    const int col = blockIdx.x * 256 + t;
    const int i0 = blockIdx.y * CH;
#pragma unroll
    for (int idx = t; idx < 16 * CH; idx += 256) {
        int b = idx / CH, i = idx % CH;
        float v = in[b * IF + i0 + i];
        if (RELU_IN) v = fmaxf(v, 0.f);
        ins[idx] = v;
    }
    __syncthreads();
    float acc[16];
#pragma unroll
    for (int b = 0; b < 16; ++b) acc[b] = 0.f;
#pragma unroll 4
    for (int i = 0; i < CH; ++i) {
        float wv = W[(size_t)(i0 + i) * OF + col];
#pragma unroll
        for (int b = 0; b < 16; ++b) acc[b] += ins[b * CH + i] * wv;
    }
#pragma unroll
    for (int b = 0; b < 16; ++b) atomicAdd(out + b * OF + col, acc[b]);
}

__global__ __launch_bounds__(64) void mlp3_kernel(const float* __restrict__ h2,
                                                  const float* __restrict__ W3,
                                                  const float* __restrict__ b3,
                                                  float* __restrict__ out)
{
    int b = blockIdx.x, t = threadIdx.x;
    float a0 = 0.f, a1 = 0.f, a2 = 0.f;
    for (int i = t; i < 512; i += 64) {
        float hv = fmaxf(h2[b * 512 + i], 0.f);
        a0 += hv * W3[i * 3 + 0];
        a1 += hv * W3[i * 3 + 1];
        a2 += hv * W3[i * 3 + 2];
    }
#pragma unroll
    for (int d = 1; d < 64; d <<= 1) {
        a0 += __shfl_xor(a0, d);
        a1 += __shfl_xor(a1, d);
        a2 += __shfl_xor(a2, d);
    }
    if (t == 0) {
        out[b * 3 + 0] = a0 + b3[0];
        out[b * 3 + 1] = a1 + b3[1];
        out[b * 3 + 2] = a2 + b3[2];
    }
}

// ---------------------------------------------------------------- launch
extern "C" void kernel_launch(void* const* d_in, const int* in_sizes, int n_in,
                              void* d_out, int out_size, void* d_ws, size_t ws_size,
                              hipStream_t stream)
{
    const float* emb  = (const float*)d_in[0];
    const float* mask = (const float*)d_in[1];
    const float* W1 = (const float*)d_in[22];
    const float* b1 = (const float*)d_in[23];
    const float* W2 = (const float*)d_in[24];
    const float* b2 = (const float*)d_in[25];
    const float* W3 = (const float*)d_in[26];
    const float* b3 = (const float*)d_in[27];

    char* ws = (char*)d_ws;
    constexpr size_t MB = 1ull << 20;
    __bf16* A     = (__bf16*)(ws);
    __bf16* Wt    = (__bf16*)(ws + 32 * MB);
    __bf16* Qb    = (__bf16*)(ws + 48 * MB);
    __bf16* Kb    = (__bf16*)(ws + 80 * MB);
    __bf16* Vt    = (__bf16*)(ws + 112 * MB);
    __bf16* attb  = (__bf16*)(ws);                 // alias A (dead after QKV gemm)
    float*  Of    = (float*) (ws + 48 * MB);       // alias Qb+Kb (dead after attn)
    float*  feats = (float*) (ws + 144 * MB);
    float*  h1    = (float*) (ws + 144 * MB + 512 * 1024);
    float*  h2    = (float*) (ws + 145 * MB);
    float2* stats = (float2*)(ws + 146 * MB);      // 128 KB
    float*  ssum  = (float*) (ws + 147 * MB);      // 64 KB, sqsum contiguous after
    float*  sqsum = ssum + 16384;

    cast_emb_kernel<<<8192, 256, 0, stream>>>(emb, A);
    WPtrs wp;
    const int widx[8] = {2, 4, 6, 8, 12, 14, 16, 18};
    for (int i = 0; i < 8; ++i) wp.p[i] = (const float*)d_in[widx[i]];
    cast_wt_kernel<<<dim3(32, 32, 8), dim3(32, 8), 0, stream>>>(wp, Wt);
    fc_init_kernel<<<224, 256, 0, stream>>>(b1, b2, h1, h2, ssum);  // also zeroes ssum/sqsum

    GArgs gqkv = {}, go = {};
    LnW lw;
    for (int dir = 0; dir < 2; ++dir) {
        const int base = dir ? 12 : 2;
        gqkv.w[dir] = Wt + (size_t)(dir * 4) * 1048576;
        gqkv.bias[dir * 3 + 0] = (const float*)d_in[base + 1];
        gqkv.bias[dir * 3 + 1] = (const float*)d_in[base + 3];
        gqkv.bias[dir * 3 + 2] = (const float*)d_in[base + 5];
        go.w[dir] = Wt + (size_t)(dir * 4 + 3) * 1048576;
        go.bias[dir * 3] = (const float*)d_in[base + 7];
        lw.g[dir] = (const float*)d_in[base + 8];
        lw.b[dir] = (const float*)d_in[base + 9];
    }
    gqkv.Qb = Qb; gqkv.Kb = Kb; gqkv.Vt = Vt;
    go.Cf = Of; go.resid = emb; go.ssum = ssum; go.sqsum = sqsum;

    gemm_bt<5><<<3072, 256, 0, stream>>>(A, gqkv, 24);
    attn_kernel<<<4096, 256, 0, stream>>>(Qb, Kb, Vt, mask, attb);
    gemm_bt<2><<<1024, 256, 0, stream>>>(attb, go, 8);
    ln_finalize_kernel<<<64, 256, 0, stream>>>(ssum, sqsum, stats);
    pool_ln_kernel<<<dim3(16, 16, 2), 256, 0, stream>>>(Of, stats, mask, lw, feats);
    pool_f32_kernel<<<dim3(16, 16, 2), 256, 0, stream>>>(emb, mask, feats);

    fc_atomic_kernel<128, 0><<<dim3(4, 32), 256, 0, stream>>>(feats, W1, h1, 4096, 1024);
    fc_atomic_kernel<32, 1><<<dim3(2, 32), 256, 0, stream>>>(h1, W2, h2, 1024, 512);
    mlp3_kernel<<<16, 64, 0, stream>>>(h2, W3, b3, (float*)d_out);
}